// Round 1
// 1640.225 us; speedup vs baseline: 1.7485x; 1.7485x over previous
//
#include <hip/hip_runtime.h>
#include <cstddef>
#include <cstdint>

// CT-LSTM right-to-left scan, weight-stationary MFMA version.
// 128 seqs (B=16,P=8), T=256, H=256, 7H=1792 gate rows, VOCAB=35, IDX_PAD=34.
//
//   z = EW[event]  +  h @ W2^T        (W2 = W[:,256:512], f16)
//
// 8 groups x 16 blocks. Group g owns seqs [16g,16g+16); block b in group owns
// hidden j in [16b,16b+16) => 7 MFMA N-tiles (one per gate), B-fragments
// resident in VGPRs for all 255 steps (zero per-step weight traffic).
// Per step: coherent h load -> 16x16x32 f16 MFMA -> LDS gate exchange ->
// epilogue -> agent-scope h' publish + per-block release flag; 16-flag
// cache-line spin for sync. h double-buffered in workspace.

typedef _Float16 hf;
typedef _Float16 f16x8 __attribute__((ext_vector_type(8)));
typedef float    f32x4 __attribute__((ext_vector_type(4)));

#define HID  256
#define R7   1792
#define TT   256
#define NPAD 34
#define NBLK 16          // blocks per group
#define HBUF_HF 4096     // f16 elems per h buffer (16 seq x 256)

__device__ __forceinline__ float sigf(float x) { return 1.0f / (1.0f + __expf(-x)); }
__device__ __forceinline__ float tanh_f(float x) { return 1.0f - 2.0f / (__expf(2.0f * x) + 1.0f); }
__device__ __forceinline__ float softplusf(float x) {
  return fmaxf(x, 0.0f) + __logf(1.0f + __expf(-fabsf(x)));
}

// ---------------------------------------------------------------------------
// Repack W[:,256:512] into MFMA B-fragment order.
// Entry idx = ((b*7+g)*8 + kt)*64 + lane  (16 B each):
//   B[k = kt*32 + 8*(lane>>4) + e][n = lane&15] = W2[row = g*256 + 16b + (lane&15)][k]
// A is packed with the SAME lane->k map, so the exact HW k-grouping cancels.
__global__ __launch_bounds__(256) void repack_mfma(const float* __restrict__ W,
                                                   f16x8* __restrict__ Wf) {
  int idx  = blockIdx.x * 256 + threadIdx.x;  // [0, 57344)
  int lane = idx & 63;
  int kt   = (idx >> 6) & 7;
  int gb   = idx >> 9;            // b*7 + g
  int g    = gb % 7;
  int b    = gb / 7;
  int row  = g * HID + b * 16 + (lane & 15);
  int k0   = kt * 32 + (lane >> 4) * 8;
  const float* src = W + (size_t)row * 512 + 256 + k0;
  f16x8 o;
#pragma unroll
  for (int e = 0; e < 8; ++e) o[e] = (hf)src[e];
  Wf[idx] = o;
}

// ---------------------------------------------------------------------------
// EW[e][r] = sum_k Emb[e][k] * W[r][k] + b[r]   (e<35, r<1792, k<256)
__global__ __launch_bounds__(256) void ew_kernel(const float* __restrict__ Emb,
                                                 const float* __restrict__ W,
                                                 const float* __restrict__ bias,
                                                 float* __restrict__ EW) {
  int wid  = (blockIdx.x * 256 + threadIdx.x) >> 6;
  int lane = threadIdx.x & 63;
  int o    = wid * 4;
#pragma unroll
  for (int q = 0; q < 4; ++q, ++o) {
    int e = o / R7;
    int r = o - e * R7;
    const float4 ev4 = *(const float4*)(Emb + e * HID + lane * 4);
    const float4 wv4 = *(const float4*)(W + (size_t)r * 512 + lane * 4);
    float acc = ev4.x * wv4.x + ev4.y * wv4.y + ev4.z * wv4.z + ev4.w * wv4.w;
#pragma unroll
    for (int m = 32; m >= 1; m >>= 1) acc += __shfl_xor(acc, m, 64);
    if (lane == 0) EW[o] = acc + bias[r];
  }
}

// ---------------------------------------------------------------------------
__global__ __launch_bounds__(256, 1) void scan_mfma(
    const int* __restrict__ event, const float* __restrict__ dtime,
    const float* __restrict__ EW, const f16x8* __restrict__ Wf,
    hf* __restrict__ hbuf, int* __restrict__ flags,
    float* __restrict__ out) {
  const int tid = threadIdx.x;
  const int grp = blockIdx.x >> 4;   // 0..7
  const int b   = blockIdx.x & 15;   // hidden slice
  const int s0  = grp * 16;
  const int j0  = b * 16;
  const int wid = tid >> 6, lane = tid & 63;
  const int seq = tid >> 4, jj = tid & 15;   // epilogue ownership
  const int j   = j0 + jj;

  __shared__ int   evs[16][TT];
  __shared__ float dts[16][TT];
  __shared__ float gbuf[7][16][20];  // [gate][jj][seq], padded: 2-way-free reads

#pragma unroll 4
  for (int r = 0; r < 16; ++r) {
    evs[r][tid] = event[(size_t)(s0 + r) * TT + tid];
    dts[r][tid] = dtime[(size_t)(s0 + r) * TT + tid];
  }
  __syncthreads();

  // Resident B fragments: wave w owns gates {2w, 2w+1} (w==3: gate 6 only).
  const int  g0  = 2 * wid;
  const bool two = (wid < 3);
  f16x8 B0[8], B1[8];
  {
    const f16x8* wsrc = Wf + (size_t)((b * 7 + g0) * 8) * 64 + lane;
#pragma unroll
    for (int kt = 0; kt < 8; ++kt) B0[kt] = wsrc[kt * 64];
    if (two) {
#pragma unroll
      for (int kt = 0; kt < 8; ++kt) B1[kt] = wsrc[(8 + kt) * 64];
    }
  }

  int* fl   = flags + grp * NBLK;
  hf*  hgrp = hbuf + (size_t)grp * (2 * HBUF_HF);

  // h' store offset in A-fragment order: lane = seq + 16*((j>>3)&3),
  // elem = j&7, tile = j>>5. Even-jj threads store packed u32 pairs.
  const int off16 = ((j >> 5) * 64 + seq + 16 * ((j >> 3) & 3)) * 8 + (j & 7);

  float cp = 0.f, cb = 0.f;
  const size_t OS = 8355840;  // per-output-tensor stride

  for (int it = 0; it < 255; ++it) {
    const int   i  = 255 - it;
    const int   t  = i - 1;
    const int   ev = evs[seq][i];
    const float dt = dts[seq][i];

    // Prefetch EW rows (event is static -> no dependency on the sync).
    float a_ew[7];
    {
      const float* Ep = EW + (size_t)ev * R7 + j;
#pragma unroll
      for (int g = 0; g < 7; ++g) a_ew[g] = Ep[g * HID];
    }

    // Wait for all 16 blocks of the group to have published iteration it-1.
    if (it > 0 && tid < NBLK) {
      int guard = 0;
      while (__hip_atomic_load(&fl[tid], __ATOMIC_ACQUIRE,
                               __HIP_MEMORY_SCOPE_AGENT) < it) {
        if (++guard > (1 << 20)) break;  // bail-out: fail verify, don't hang
      }
    }
    __syncthreads();  // B1: h ready; gbuf free for rewrite

    f32x4 acc0 = {0.f, 0.f, 0.f, 0.f}, acc1 = {0.f, 0.f, 0.f, 0.f};
    if (it > 0) {
      // Coherent A-fragment loads: lane l reads h[seq=l&15][k=32kt+8(l>>4)+e].
      const hf* hp = hgrp + (size_t)(it & 1) * HBUF_HF + (size_t)lane * 8;
      f16x8 av[8];
#pragma unroll
      for (int kt = 0; kt < 8; ++kt) {
        asm volatile("global_load_dwordx4 %0, %1, off sc0 sc1"
                     : "=v"(av[kt])
                     : "v"(hp + (size_t)kt * 512));
      }
      asm volatile("s_waitcnt vmcnt(0)" ::: "memory");
      __builtin_amdgcn_sched_barrier(0);
#pragma unroll
      for (int kt = 0; kt < 8; ++kt) {
        acc0 = __builtin_amdgcn_mfma_f32_16x16x32_f16(av[kt], B0[kt], acc0, 0, 0, 0);
        if (two)
          acc1 = __builtin_amdgcn_mfma_f32_16x16x32_f16(av[kt], B1[kt], acc1, 0, 0, 0);
      }
    }

    // C/D: lane l, reg r -> D[seq=4*(l>>4)+r][n=l&15]  (verified layout).
    {
      const int q = lane >> 4, n = lane & 15;
      *(f32x4*)&gbuf[g0][n][4 * q] = acc0;
      if (two) *(f32x4*)&gbuf[g0 + 1][n][4 * q] = acc1;
    }
    __syncthreads();  // B2: all 7 gate tiles visible

    // Epilogue for (seq, jj).
    float zz[7];
#pragma unroll
    for (int g = 0; g < 7; ++g) zz[g] = a_ew[g] + gbuf[g][jj][seq];
    float gi  = sigf(zz[0]), gf = sigf(zz[1]), go = sigf(zz[2]);
    float gz  = tanh_f(zz[3]);
    float gib = sigf(zz[4]), gfb = sigf(zz[5]);
    float gd  = softplusf(zz[6]);
    float cell = gf * cp + gi * gz;
    float cbar = gfb * cb + gib * gz;
    float hm   = go * tanh_f(cell);
    float dec  = __expf(-gd * dt);
    float cim  = cbar + (cell - cbar) * dec;
    float him  = go * tanh_f(cim);
    float msk  = (ev != NPAD) ? 1.0f : 0.0f;
    float cbm  = cbar * msk;
    float hn   = him * msk;

    float* o = out + (size_t)(s0 + seq) * 65280 + (size_t)t * HID + j;
    o[0] = cell; o[OS] = cbm; o[2 * OS] = gd; o[3 * OS] = go;
    o[4 * OS] = hn; o[5 * OS] = hm;
    cp = cim * msk;
    cb = cbm;

    // Publish h' (agent-scope so it reaches the coherence point).
    unsigned short hb16 = __builtin_bit_cast(unsigned short, (hf)hn);
    unsigned nb = __shfl_down((unsigned)hb16, 1, 64);
    if (!(jj & 1)) {
      unsigned pack = (unsigned)hb16 | (nb << 16);
      hf* hw = hgrp + (size_t)((it + 1) & 1) * HBUF_HF;
      __hip_atomic_store((unsigned*)(hw + off16), pack, __ATOMIC_RELAXED,
                         __HIP_MEMORY_SCOPE_AGENT);
    }
    __syncthreads();  // B3: every wave's stores drained (vmcnt 0) pre-flag
    if (tid == 0 && it < 254)
      __hip_atomic_store(&fl[b], it + 1, __ATOMIC_RELEASE,
                         __HIP_MEMORY_SCOPE_AGENT);
  }
}

// ---------------------------------------------------------------------------
extern "C" void kernel_launch(void* const* d_in, const int* in_sizes, int n_in,
                              void* d_out, int out_size, void* d_ws, size_t ws_size,
                              hipStream_t stream) {
  const int*   event = (const int*)d_in[0];
  const float* dtime = (const float*)d_in[1];
  const float* Emb   = (const float*)d_in[2];
  const float* W     = (const float*)d_in[3];
  const float* bias  = (const float*)d_in[4];
  float*       out   = (float*)d_out;

  char*  ws = (char*)d_ws;
  f16x8* Wf = (f16x8*)ws;                               // 57344*16 = 917504 B
  float* EW = (float*)(ws + 917504);                    // 35*1792*4 = 250880 B
  hf*    hb = (hf*)(ws + 917504 + 250880);              // 8 grp * 2 * 8 KB = 131072 B
  int*   fl = (int*)(ws + 917504 + 250880 + 131072);    // 8*16*4 = 512 B

  // h buffers + flags must be zero each launch (graph replay re-runs this).
  hipMemsetAsync(ws + 917504 + 250880, 0, 131072 + 512, stream);
  repack_mfma<<<224, 256, 0, stream>>>(W, Wf);
  ew_kernel<<<3920, 256, 0, stream>>>(Emb, W, bias, EW);
  scan_mfma<<<128, 256, 0, stream>>>(event, dtime, EW, Wf, hb, fl, out);
}

// Round 3
// 1146.124 us; speedup vs baseline: 2.5023x; 1.4311x over previous
//
#include <hip/hip_runtime.h>
#include <cstddef>
#include <cstdint>

// CT-LSTM right-to-left scan, weight-stationary MFMA, 2-cohort pipeline.
// 128 seqs (B=16,P=8), T=256, H=256, 7H=1792 gate rows, VOCAB=35, IDX_PAD=34.
//
//   z = EW[event]  +  h @ W2^T        (W2 = W[:,256:512], f16)
//
// 16 slices x 4 super-groups = 64 blocks. Block (b,p) holds B-fragments for
// hidden j in [16b,16b+16) resident in VGPRs for all 255 steps, and
// alternates TWO cohorts of 16 seqs. EW is folded into the MFMA accumulator
// init (C-in), so the epilogue is pure LDS+VALU.
//
// Coherence protocol (relaxed everywhere; no acquire-inv / release-wb so L2
// stays warm):
//   - h' publish + flags: __hip_atomic_store relaxed agent (write-through to
//     the L3 coherence point; proven pairing from round 1)
//   - every half begins with s_waitcnt vmcnt(0) -> own publishes are L3-acked
//     -> barrier -> flag release afterwards: any observer of flag==v sees all
//     h' data for iteration v.
//   - h loads: inline-asm global_load_dwordx4 sc0 sc1 (bypass L1/L2).
//   - flag probe issued at END of previous half (compiler-tracked load;
//     compiler inserts the mandatory waitcnt before use -- round-2's bug was
//     reading an inline-asm load result without a waitcnt).

typedef _Float16 hf;
typedef _Float16 f16x8 __attribute__((ext_vector_type(8)));
typedef float    f32x4 __attribute__((ext_vector_type(4)));

#define HID  256
#define R7   1792
#define TT   256
#define NPAD 34
#define HBUF_HF 4096     // f16 elems per h buffer (16 seq x 256)

__device__ __forceinline__ float sigf(float x) { return 1.0f / (1.0f + __expf(-x)); }
__device__ __forceinline__ float tanh_f(float x) { return 1.0f - 2.0f / (__expf(2.0f * x) + 1.0f); }
__device__ __forceinline__ float softplusf(float x) {
  return fmaxf(x, 0.0f) + __logf(1.0f + __expf(-fabsf(x)));
}

// ---------------------------------------------------------------------------
// Repack W[:,256:512] into MFMA B-fragment order.
// Entry idx = ((b*7+g)*8 + kt)*64 + lane:
//   B[k = kt*32 + 8*(lane>>4) + e][n = lane&15] = W2[g*256 + 16b + (lane&15)][k]
__global__ __launch_bounds__(256) void repack_mfma(const float* __restrict__ W,
                                                   f16x8* __restrict__ Wf) {
  int idx  = blockIdx.x * 256 + threadIdx.x;  // [0, 57344)
  int lane = idx & 63;
  int kt   = (idx >> 6) & 7;
  int gb   = idx >> 9;            // b*7 + g
  int g    = gb % 7;
  int b    = gb / 7;
  int row  = g * HID + b * 16 + (lane & 15);
  int k0   = kt * 32 + (lane >> 4) * 8;
  const float* src = W + (size_t)row * 512 + 256 + k0;
  f16x8 o;
#pragma unroll
  for (int e = 0; e < 8; ++e) o[e] = (hf)src[e];
  Wf[idx] = o;
}

// ---------------------------------------------------------------------------
// EW[e][r] = sum_k Emb[e][k] * W[r][k] + b[r]   (e<35, r<1792, k<256)
__global__ __launch_bounds__(256) void ew_kernel(const float* __restrict__ Emb,
                                                 const float* __restrict__ W,
                                                 const float* __restrict__ bias,
                                                 float* __restrict__ EW) {
  int wid  = (blockIdx.x * 256 + threadIdx.x) >> 6;
  int lane = threadIdx.x & 63;
  int o    = wid * 4;
#pragma unroll
  for (int qq = 0; qq < 4; ++qq, ++o) {
    int e = o / R7;
    int r = o - e * R7;
    const float4 ev4 = *(const float4*)(Emb + e * HID + lane * 4);
    const float4 wv4 = *(const float4*)(W + (size_t)r * 512 + lane * 4);
    float acc = ev4.x * wv4.x + ev4.y * wv4.y + ev4.z * wv4.z + ev4.w * wv4.w;
#pragma unroll
    for (int m = 32; m >= 1; m >>= 1) acc += __shfl_xor(acc, m, 64);
    if (lane == 0) EW[o] = acc + bias[r];
  }
}

// ---------------------------------------------------------------------------
__global__ __launch_bounds__(256, 1) void scan_mfma(
    const int* __restrict__ event, const float* __restrict__ dtime,
    const float* __restrict__ EW, const f16x8* __restrict__ Wf,
    hf* __restrict__ hbuf, int* __restrict__ flags,
    float* __restrict__ out) {
  const int tid = threadIdx.x;
  const int b   = blockIdx.x & 15;   // hidden slice
  const int p   = blockIdx.x >> 4;   // super-group 0..3
  const int j0  = b * 16;
  const int wid = tid >> 6, lane = tid & 63;
  const int seq = tid >> 4, jj = tid & 15;   // epilogue ownership (per cohort)
  const int j   = j0 + jj;
  const int q   = lane >> 4, nn = lane & 15; // MFMA C/D coords

  __shared__ int   evs[32][TT];              // [cohort*16+seq][i]
  __shared__ float dts[32][TT];
  __shared__ __align__(16) float gbuf[7][16][20];  // [gate][n][seq] (pad 20)

#pragma unroll 4
  for (int r = 0; r < 32; ++r) {
    evs[r][tid] = event[(size_t)(p * 32 + r) * TT + tid];
    dts[r][tid] = dtime[(size_t)(p * 32 + r) * TT + tid];
  }

  // Resident B fragments: wave w owns gates {2w, 2w+1} (w==3: gate 6 only).
  const int  g0  = 2 * wid;
  const bool two = (wid < 3);
  f16x8 B0[8], B1[8];
  {
    const f16x8* wsrc = Wf + (size_t)((b * 7 + g0) * 8) * 64 + lane;
#pragma unroll
    for (int kt = 0; kt < 8; ++kt) B0[kt] = wsrc[kt * 64];
    if (two) {
#pragma unroll
      for (int kt = 0; kt < 8; ++kt) B1[kt] = wsrc[(8 + kt) * 64];
    }
  }
  __syncthreads();

  int* flb = flags + p * 64;                 // [cohort][32-int padded]
  hf*  hpb = hbuf + (size_t)p * 4 * HBUF_HF; // [cohort][dbuf][4096]

  // h' store offset in A-fragment order (same lane->k map as the reader).
  const int off16 = ((j >> 5) * 64 + seq + 16 * ((j >> 3) & 3)) * 8 + (j & 7);
  const size_t OS = 8355840;  // per-output-tensor stride

  float cp0 = 0.f, cb0 = 0.f, cp1 = 0.f, cb1 = 0.f;
  int pr = 0;  // probe value (compiler-tracked load result)

  auto body = [&](const int c, const int it, float& cp, float& cb) {
    const int   i  = 255 - it, t = i - 1;
    const int   cs = c * 16 + seq;
    const int   ev = evs[cs][i];
    const float dt = dts[cs][i];
    int* flc = flb + c * 32;

    // ---- A: drain (publishes of previous half L3-acked; probe valid) ----
    asm volatile("s_waitcnt vmcnt(0)" ::: "memory");
    __builtin_amdgcn_sched_barrier(0);
    if (it > 0) {
      int pv = (nn == b) ? 0x7fffffff : pr;  // own flag known-by-construction
      if (!__all(pv >= it)) {
        int gd = 0;
        for (;;) {  // relaxed poll: no cache invalidation, L2 stays warm
          int v = (nn == b) ? 0x7fffffff
                : __hip_atomic_load(&flc[nn], __ATOMIC_RELAXED,
                                    __HIP_MEMORY_SCOPE_AGENT);
          if (__all(v >= it) || ++gd > (1 << 20)) break;  // bail: fail, no hang
        }
      }
    }

    // ---- B: issue h loads (L3 RT hides under barrier) + EW gather ----
    f16x8 av[8];
    if (it > 0) {
      const hf* hp = hpb + (size_t)(c * 2 + (it & 1)) * HBUF_HF + (size_t)lane * 8;
#pragma unroll
      for (int kt = 0; kt < 8; ++kt)
        asm volatile("global_load_dwordx4 %0, %1, off sc0 sc1"
                     : "=v"(av[kt]) : "v"(hp + (size_t)kt * 512));
    }
    float e0[4], e1[4];
#pragma unroll
    for (int r = 0; r < 4; ++r) {  // EW for (gate, seq=4q+r, col nn) -> C-in
      const int evr = evs[c * 16 + 4 * q + r][i];
      const float* Ep = EW + (size_t)evr * R7 + j0 + nn;
      e0[r] = Ep[g0 * HID];
      e1[r] = two ? Ep[(g0 + 1) * HID] : 0.0f;
    }

    // ---- C: barrier (gbuf WAR + all-waves-drained before flag release) ----
    asm volatile("" ::: "memory");
    __builtin_amdgcn_s_barrier();
    asm volatile("" ::: "memory");

    // ---- E: wait h (+EW) ----
    asm volatile("s_waitcnt vmcnt(0)" ::: "memory");
    __builtin_amdgcn_sched_barrier(0);

    // ---- D: release flag for the PREVIOUS half's cohort (c^1). Its
    // publishes were drained by every wave at step A, barrier'd at C. Placed
    // after E so no later wait ever stalls on this store's ack. ----
    if (tid == 0 && (c == 1 || it > 0)) {
      const int fv = (c == 0) ? it : it + 1;
      __hip_atomic_store(&flb[(c ^ 1) * 32 + b], fv, __ATOMIC_RELAXED,
                         __HIP_MEMORY_SCOPE_AGENT);
    }

    // ---- F: MFMA, accumulators pre-loaded with EW (C-in = EW) ----
    f32x4 acc0 = {e0[0], e0[1], e0[2], e0[3]};
    f32x4 acc1 = {e1[0], e1[1], e1[2], e1[3]};
    if (it > 0) {
#pragma unroll
      for (int kt = 0; kt < 8; ++kt) {
        acc0 = __builtin_amdgcn_mfma_f32_16x16x32_f16(av[kt], B0[kt], acc0, 0, 0, 0);
        if (two)
          acc1 = __builtin_amdgcn_mfma_f32_16x16x32_f16(av[kt], B1[kt], acc1, 0, 0, 0);
      }
    }

    // ---- G: gate exchange. C/D: lane l, reg r -> D[seq=4*(l>>4)+r][n=l&15]
    *(f32x4*)&gbuf[g0][nn][4 * q] = acc0;
    if (two) *(f32x4*)&gbuf[g0 + 1][nn][4 * q] = acc1;
    asm volatile("s_waitcnt lgkmcnt(0)" ::: "memory");
    __builtin_amdgcn_s_barrier();
    __builtin_amdgcn_sched_barrier(0);

    // ---- H: epilogue for (seq, jj) — pure LDS+VALU ----
    float zz[7];
#pragma unroll
    for (int g = 0; g < 7; ++g) zz[g] = gbuf[g][jj][seq];
    float gi = sigf(zz[0]), gf = sigf(zz[1]), go = sigf(zz[2]);
    float gz = tanh_f(zz[3]);
    float gib = sigf(zz[4]), gfb = sigf(zz[5]);
    float gd = softplusf(zz[6]);
    float cell = gf * cp + gi * gz;
    float cbar = gfb * cb + gib * gz;
    float hm   = go * tanh_f(cell);
    float dec  = __expf(-gd * dt);
    float cim  = cbar + (cell - cbar) * dec;
    float him  = go * tanh_f(cim);
    float msk  = (ev != NPAD) ? 1.0f : 0.0f;
    float cbm  = cbar * msk;
    float hn   = him * msk;
    cp = cim * msk;
    cb = cbm;

    // ---- I: publish h' (relaxed agent store -> drained at next half's A) ----
    unsigned short hb16 = __builtin_bit_cast(unsigned short, (hf)hn);
    unsigned nb = __shfl_down((unsigned)hb16, 1, 64);
    if (it < 254 && !(jj & 1)) {
      unsigned pack = (unsigned)hb16 | (nb << 16);
      hf* hw = hpb + (size_t)(c * 2 + ((it + 1) & 1)) * HBUF_HF;
      __hip_atomic_store((unsigned*)(hw + off16), pack, __ATOMIC_RELAXED,
                         __HIP_MEMORY_SCOPE_AGENT);
    }

    // ---- J: probe next cohort's flags (compiler-tracked; waitcnt inserted
    // by the compiler before first use at next half's step A) ----
    pr = __hip_atomic_load(&flb[(c ^ 1) * 32 + nn], __ATOMIC_RELAXED,
                           __HIP_MEMORY_SCOPE_AGENT);

    // ---- K: output stores (off the critical path) ----
    float* o = out + (size_t)(p * 32 + cs) * 65280 + (size_t)t * HID + j;
    o[0] = cell; o[OS] = cbm; o[2 * OS] = gd; o[3 * OS] = go;
    o[4 * OS] = hn; o[5 * OS] = hm;
  };

#pragma unroll 1
  for (int it = 0; it < 255; ++it) {
    body(0, it, cp0, cb0);
    body(1, it, cp1, cb1);
  }
}

// ---------------------------------------------------------------------------
extern "C" void kernel_launch(void* const* d_in, const int* in_sizes, int n_in,
                              void* d_out, int out_size, void* d_ws, size_t ws_size,
                              hipStream_t stream) {
  const int*   event = (const int*)d_in[0];
  const float* dtime = (const float*)d_in[1];
  const float* Emb   = (const float*)d_in[2];
  const float* W     = (const float*)d_in[3];
  const float* bias  = (const float*)d_in[4];
  float*       out   = (float*)d_out;

  char*  ws = (char*)d_ws;
  f16x8* Wf = (f16x8*)ws;                               // 917504 B
  float* EW = (float*)(ws + 917504);                    // 250880 B
  hf*    hb = (hf*)(ws + 917504 + 250880);              // 4p*2c*2buf*8KB = 131072 B
  int*   fl = (int*)(ws + 917504 + 250880 + 131072);    // 4p*2c*32 ints = 1024 B

  // h buffers + flags must be zero each launch (graph replay re-runs this).
  hipMemsetAsync(ws + 917504 + 250880, 0, 131072 + 1024, stream);
  repack_mfma<<<224, 256, 0, stream>>>(W, Wf);
  ew_kernel<<<3920, 256, 0, stream>>>(Emb, W, bias, EW);
  scan_mfma<<<64, 256, 0, stream>>>(event, dtime, EW, Wf, hb, fl, out);
}